// Round 5
// baseline (155.821 us; speedup 1.0000x reference)
//
#include <hip/hip_runtime.h>
#include <stdint.h>

#define BATCH 32
#define HDIM 224
#define WDIM 224
#define CDIM 3
#define KTOT (HDIM * WDIM * CDIM)   // 150528
#define HID 64
#define KCHUNK 128
#define NBLK1 (KTOT / KCHUNK)       // 1176
#define PIX (HDIM * WDIM)           // 50176
#define BLK3 49                      // blocks per batch: 1024 thr * 1 px

#define NSHARD 8
#define BH (BATCH * HID)             // 2048
#define HACC_BYTES (NSHARD * BH * 4) // 64 KB: 8 shards, k3 sums them
#define PART_BYTES ((size_t)NBLK1 * BH * 4)  // 9.63 MB

typedef float float2v __attribute__((ext_vector_type(2)));
typedef float float4v __attribute__((ext_vector_type(4)));
// 4-byte-aligned vector loads (texel addresses are only 4B aligned)
typedef float float4u __attribute__((ext_vector_type(4), aligned(4)));
typedef float float2u __attribute__((ext_vector_type(2), aligned(4)));

// Direct global->LDS DMA: no VGPR results => nothing for the compiler to
// sink into the FMA loop. Rounds 0/2/4 proved reg-prefetch of w1 is sunk
// (VGPR=40 -> 8 serialized ~900cy stall rounds/block = the 40us wall);
// round 1 proved asm pins spill everything (WRITE_SIZE=192MB).
#define GLDS(gp, lp)                                                          \
    __builtin_amdgcn_global_load_lds(                                         \
        (const __attribute__((address_space(1))) uint32_t*)(const void*)(gp), \
        (__attribute__((address_space(3))) uint32_t*)(void*)(lp), 16, 0, 0)

// ---------------- Kernel 1: part[blk] = flat @ w1 slice (split-K) -----------
// Block: 256 thr = 4 waves, owns k-range [k0, k0+128).
// LDS: flat tile 16 KB ([32][128], words 0..4095) + w1 tile 32 KB ([128][64],
// words 4096..12287; contiguous 32 KB chunk of global). Both staged with
// global_load_lds -> ONE vmcnt drain per block; 3 blocks/CU overlap it.
// Thread: kh = lane>>5 picks the 16-k half, hp = lane&31 picks hid pair
// (2hp, 2hp+1). Each ds_read_b128 of flat feeds 8 FMAs (4k x 2hid).
// Epilogue: plain coalesced store of the block partial (round-3's 2.4M
// same-address atomics = serialized RMW wall, removed in round 4).
__global__ __launch_bounds__(256, 3) void k1_gemm(const float* __restrict__ flat,
                                                  const float* __restrict__ w1,
                                                  float* __restrict__ hacc,
                                                  float* __restrict__ part) {
    __shared__ float smem[12288];                // 48 KB -> 3 blocks/CU
    const int tid  = threadIdx.x;
    const int lane = tid & 63;
    const int wave = tid >> 6;
    const int k0   = blockIdx.x * KCHUNK;

    // --- Stage flat[32][k0..k0+128): 16 chunks of 1 KB, wave-linear LDS ---
#pragma unroll
    for (int t = 0; t < 4; ++t) {
        const int c = t * 4 + wave;              // chunk 0..15
        const int f = c * 64 + lane;             // float4 index 0..1023
        const int b = f >> 5;
        const int kq = f & 31;
        GLDS(flat + (size_t)b * KTOT + k0 + kq * 4, smem + c * 256);
    }
    // --- Stage w1[k0..k0+128)[0..64): one contiguous 32 KB global chunk ---
#pragma unroll
    for (int t = 0; t < 8; ++t) {
        const int c = t * 4 + wave;              // chunk 0..31
        const int f = c * 64 + lane;             // float4 index 0..2047
        GLDS(w1 + (size_t)k0 * HID + (size_t)f * 4, smem + 4096 + c * 256);
    }
    __syncthreads();                             // drains vmcnt for the DMA

    const int kh    = lane >> 5;                 // 16-k subrange within wave
    const int hp    = lane & 31;                 // hid pair index
    const int kbase = wave * 32 + kh * 16;

    // w slice LDS->regs (16 x ds_read_b64, 2-way bank alias = free)
    float wx[16], wy[16];
#pragma unroll
    for (int i = 0; i < 16; ++i) {
        const float2v t = *(const float2v*)(smem + 4096 + (kbase + i) * 64 + hp * 2);
        wx[i] = t.x; wy[i] = t.y;
    }

    float2v acc[32];
#pragma unroll
    for (int b = 0; b < 32; ++b) { acc[b].x = 0.0f; acc[b].y = 0.0f; }

    // 8 FMAs per ds_read_b128; flat address uniform per half-wave (broadcast)
#pragma unroll
    for (int kk = 0; kk < 16; kk += 4) {
#pragma unroll
        for (int b = 0; b < 32; ++b) {
            const float4v x = *(const float4v*)(smem + b * 128 + kbase + kk);
            float2v a = acc[b];
            a.x = fmaf(x.x, wx[kk + 0], a.x);  a.y = fmaf(x.x, wy[kk + 0], a.y);
            a.x = fmaf(x.y, wx[kk + 1], a.x);  a.y = fmaf(x.y, wy[kk + 1], a.y);
            a.x = fmaf(x.z, wx[kk + 2], a.x);  a.y = fmaf(x.z, wy[kk + 2], a.y);
            a.x = fmaf(x.w, wx[kk + 3], a.x);  a.y = fmaf(x.w, wy[kk + 3], a.y);
            acc[b] = a;
        }
    }

    // --- Fold the two kh halves: lanes l, l^32 hold the same (hp, b) ---
#pragma unroll
    for (int b = 0; b < 32; ++b) {
        acc[b].x += __shfl_xor(acc[b].x, 32);
        acc[b].y += __shfl_xor(acc[b].y, 32);
    }

    __syncthreads();                             // LDS tiles fully consumed
    // --- Waves 1..3 (lower half-lanes) dump partials; wave 0 sums + stores --
    if (wave && kh == 0) {
#pragma unroll
        for (int b = 0; b < 32; ++b)
            *(float2v*)(smem + (wave - 1) * 2048 + b * 64 + hp * 2) = acc[b];
    }
    __syncthreads();
    if (wave == 0 && kh == 0) {
        if (part) {                              // 2-stage: streaming store
            float* po = part + (size_t)blockIdx.x * BH;
#pragma unroll
            for (int b = 0; b < 32; ++b) {
                const int idx = b * 64 + hp * 2;
                float2v s;
                s.x = acc[b].x + smem[idx]     + smem[2048 + idx]     + smem[4096 + idx];
                s.y = acc[b].y + smem[idx + 1] + smem[2048 + idx + 1] + smem[4096 + idx + 1];
                *(float2v*)(po + idx) = s;
            }
        } else {                                 // fallback: sharded atomics
            float* ha = hacc + (blockIdx.x & (NSHARD - 1)) * BH;
#pragma unroll
            for (int b = 0; b < 32; ++b) {
                const int idx = b * 64 + hp * 2;
                atomicAdd(ha + idx,
                          acc[b].x + smem[idx] + smem[2048 + idx] + smem[4096 + idx]);
                atomicAdd(ha + idx + 1,
                          acc[b].y + smem[idx + 1] + smem[2048 + idx + 1] + smem[4096 + idx + 1]);
            }
        }
    }
}

// -------- Kernel 2 (2-stage mode): reduce 1176 partials -> 8 shards ---------
// 256 blocks = (batch, q). Each block owns shard slot hacc[q][b][*]: pure
// coalesced reads + ONE plain store per thread-group. Zero atomics, so the
// hacc memset is gone too. k3 sums the 8 shards.
__global__ __launch_bounds__(256) void k2_reduce(const float* __restrict__ part,
                                                 float* __restrict__ hacc) {
    const int b    = blockIdx.x >> 3;
    const int q    = blockIdx.x & 7;
    const int tid  = threadIdx.x;
    const int lane = tid & 63;
    const int wave = tid >> 6;
    const int r0   = q * 147;                    // 8 * 147 = 1176

    float s = 0.0f;
    for (int r = r0 + wave; r < r0 + 147; r += 4)
        s += part[(size_t)r * BH + b * HID + lane];

    __shared__ float red[3][64];
    if (wave) red[wave - 1][lane] = s;
    __syncthreads();
    if (wave == 0)
        hacc[q * BH + b * HID + lane] =
            s + red[0][lane] + red[1][lane] + red[2][lane];
}

// -------- Kernel 3: all-wave head + affine grid + bilinear sampling ---------
// Sampling body proven in rounds 1-4. Head: every wave redundantly sums the
// 8 shards + butterfly-reduces the 64-term theta dot -> no LDS, no barrier,
// no idle waves. Output stores are nontemporal (never re-read; keep L2 for
// the img gather).
__global__ __launch_bounds__(1024) void k3_sample(const float* __restrict__ img,
                                                  const float* __restrict__ hacc,
                                                  const float* __restrict__ b1,
                                                  const float* __restrict__ w2,
                                                  const float* __restrict__ b2,
                                                  float* __restrict__ out) {
    const int b     = blockIdx.x / BLK3;
    const int strip = blockIdx.x - b * BLK3;
    const int tid   = threadIdx.x;
    const int lane  = tid & 63;

    // --- theta, per wave: lane = hid, butterfly-sum the 64-term dot ---
    float a = 0.0f;
#pragma unroll
    for (int s = 0; s < NSHARD; ++s)
        a += hacc[s * BH + b * HID + lane];
    const float hv = tanhf(a + b1[lane]);
    const float* w2p = w2 + lane * 6;            // w2 is [HID][6] row-major
    float q[6];
#pragma unroll
    for (int t = 0; t < 6; ++t) q[t] = hv * w2p[t];
#pragma unroll
    for (int off = 32; off >= 1; off >>= 1) {
#pragma unroll
        for (int t = 0; t < 6; ++t) q[t] += __shfl_xor(q[t], off);
    }
    const float t0 = tanhf(q[0] + b2[0]);
    const float t1 = tanhf(q[1] + b2[1]);
    const float t2 = tanhf(q[2] + b2[2]);
    const float t3 = tanhf(q[3] + b2[3]);
    const float t4 = tanhf(q[4] + b2[4]);
    const float t5 = tanhf(q[5] + b2[5]);

    const float* base = img + (size_t)b * KTOT;
    const int pix = strip * 1024 + tid;
    const int i   = pix / WDIM;
    const int j   = pix - i * WDIM;

    const float xt = (2.0f * (float)j - (float)(WDIM - 1)) / (float)(WDIM - 1);
    const float yt = (2.0f * (float)i - (float)(HDIM - 1)) / (float)(HDIM - 1);

    const float xs = t0 * xt + t1 * yt + t2;
    const float ys = t3 * xt + t4 * yt + t5;

    const float x = 0.5f * (xs + 1.0f) * (float)(WDIM - 1);
    const float y = 0.5f * (ys + 1.0f) * (float)(HDIM - 1);

    const int x0 = (int)floorf(x);
    const int y0 = (int)floorf(y);

    const int x0c = min(max(x0, 0), WDIM - 1);
    const int x1c = min(max(x0 + 1, 0), WDIM - 1);
    const int y0c = min(max(y0, 0), HDIM - 1);
    const int y1c = min(max(y0 + 1, 0), HDIM - 1);

    // Reference computes weights from CLIPPED corner coordinates.
    const float x0f = (float)x0c, x1f = (float)x1c;
    const float y0f = (float)y0c, y1f = (float)y1c;

    const float wa = (x1f - x) * (y1f - y);
    const float wb = (x1f - x) * (y - y0f);
    const float wc = (x - x0f) * (y1f - y);
    const float wd = (x - x0f) * (y - y0f);

    // Both corners of a row are adjacent texels (x1c == x0c+1 whenever the
    // clamp doesn't bind); fetch each row as one 16B + one 8B load. min()
    // keeps the tail access in-bounds.
    int oA = (y0c * WDIM + x0c) * 3;
    int oB = (y1c * WDIM + x0c) * 3;
    oA = min(oA, KTOT - 6);
    oB = min(oB, KTOT - 6);
    const float4u Ar  = *(const float4u*)(base + oA);      // a0 a1 a2 c0
    const float2u Ar2 = *(const float2u*)(base + oA + 4);  // c1 c2
    const float4u Br  = *(const float4u*)(base + oB);      // b0 b1 b2 d0
    const float2u Br2 = *(const float2u*)(base + oB + 4);  // d1 d2

    const float r0 = wa * Ar.x + wb * Br.x + wc * Ar.w  + wd * Br.w;
    const float r1 = wa * Ar.y + wb * Br.y + wc * Ar2.x + wd * Br2.x;
    const float r2 = wa * Ar.z + wb * Br.z + wc * Ar2.y + wd * Br2.y;

    float* po = out + (size_t)b * KTOT + (size_t)pix * 3;
    float2u rv; rv.x = r0; rv.y = r1;
    __builtin_nontemporal_store(rv, (float2u*)po);
    __builtin_nontemporal_store(r2, po + 2);
}

extern "C" void kernel_launch(void* const* d_in, const int* in_sizes, int n_in,
                              void* d_out, int out_size, void* d_ws, size_t ws_size,
                              hipStream_t stream) {
    const float* inputs = (const float*)d_in[0];
    const float* w1     = (const float*)d_in[1];
    const float* b1     = (const float*)d_in[2];
    const float* w2     = (const float*)d_in[3];
    const float* b2     = (const float*)d_in[4];
    float* out = (float*)d_out;

    float* hacc = (float*)d_ws;                  // NSHARD * 2048 floats
    float* part = (float*)((char*)d_ws + HACC_BYTES);
    const bool two_stage = ws_size >= HACC_BYTES + PART_BYTES;

    if (!two_stage)                              // atomics need zero-init
        hipMemsetAsync(hacc, 0, HACC_BYTES, stream);
    k1_gemm<<<NBLK1, 256, 0, stream>>>(inputs, w1, hacc,
                                       two_stage ? part : (float*)nullptr);
    if (two_stage)
        k2_reduce<<<256, 256, 0, stream>>>(part, hacc);
    k3_sample<<<BATCH * BLK3, 1024, 0, stream>>>(inputs, hacc, b1, w2, b2, out);
}

// Round 6
// 142.804 us; speedup vs baseline: 1.0912x; 1.0912x over previous
//
#include <hip/hip_runtime.h>
#include <stdint.h>

#define BATCH 32
#define HDIM 224
#define WDIM 224
#define CDIM 3
#define KTOT (HDIM * WDIM * CDIM)   // 150528
#define HID 64
#define KCHUNK 64
#define NBLK1 (KTOT / KCHUNK)       // 2352
#define PIX (HDIM * WDIM)           // 50176
#define BLK3 49                      // blocks per batch: 1024 thr * 1 px

#define NSHARD 16
#define BH (BATCH * HID)             // 2048
#define HACC_BYTES (NSHARD * BH * 4) // 128 KB (shard 0 used in 2-stage mode)
#define PART_BYTES ((size_t)NBLK1 * BH * 4)  // 19.3 MB

typedef float float4v __attribute__((ext_vector_type(4)));
// 4-byte-aligned vector loads (texel addresses are only 4B aligned)
typedef float float4u __attribute__((ext_vector_type(4), aligned(4)));
typedef float float2u __attribute__((ext_vector_type(2), aligned(4)));

// Direct global->LDS DMA: no VGPR results => nothing for the compiler to sink
// into the FMA loop (rounds 0/2: reg-prefetch sunk, VGPR=40, 8 serialized
// stall rounds; round 1: asm pins spill everything, WRITE=192MB).
#define GLDS(gp, lp)                                                          \
    __builtin_amdgcn_global_load_lds(                                         \
        (const __attribute__((address_space(1))) uint32_t*)(const void*)(gp), \
        (__attribute__((address_space(3))) uint32_t*)(void*)(lp), 16, 0, 0)

// ---------------- Kernel 1: part[blk] = flat @ w1 slice (split-K) -----------
// Round-6 change vs round 5: KCHUNK 64 (was 128) -> 24 KB LDS -> 6 blocks/CU
// (was 3). Same total traffic; halves each vmcnt(0)+barrier drain and doubles
// the number of staggered block-phases per CU. Round-5 counters showed the CU
// at 9 GB/s effective (~5us per 1.1us-compute block cycle): phase
// serialization, not raw BW, is the suspect.
// LDS: flat [32][64] = 8 KB (words 0..2047) + w1 [64][64] = 16 KB (words
// 2048..6143, a contiguous 16 KB chunk of global). Thread = hid (lane), wave
// owns 16 k's. Epilogue: coalesced partial store (atomic wall removed r4).
__global__ __launch_bounds__(256, 6) void k1_gemm(const float* __restrict__ flat,
                                                  const float* __restrict__ w1,
                                                  float* __restrict__ hacc,
                                                  float* __restrict__ part) {
    __shared__ float smem[6144];                 // 24 KB
    const int tid  = threadIdx.x;
    const int lane = tid & 63;                   // hid
    const int wave = tid >> 6;
    const int k0   = blockIdx.x * KCHUNK;
    const int kw   = wave * 16;

    // --- Stage flat[32][k0..k0+64): 8 chunks of 1 KB, wave-linear LDS ---
#pragma unroll
    for (int t = 0; t < 2; ++t) {
        const int c = wave * 2 + t;              // chunk 0..7
        const int f = c * 64 + lane;             // float4 index 0..511
        const int b = f >> 4;                    // 16 float4 per batch row
        const int kq = f & 15;
        GLDS(flat + (size_t)b * KTOT + k0 + kq * 4, smem + c * 256);
    }
    // --- Stage w1[k0..k0+64)[0..64): one contiguous 16 KB global chunk ---
#pragma unroll
    for (int t = 0; t < 4; ++t) {
        const int c = t * 4 + wave;              // chunk 0..15
        const int f = c * 64 + lane;             // float4 index 0..1023
        GLDS(w1 + (size_t)k0 * HID + (size_t)f * 4, smem + 2048 + c * 256);
    }
    __syncthreads();                             // drains vmcnt for the DMA

    float acc[32];
#pragma unroll
    for (int j = 0; j < 32; ++j) acc[j] = 0.0f;

    // Per kk-iter: 4 w-reads (ds_read_b32, stride-64-word -> 2-way = free,
    // b-invariant so hoisted) + 32 broadcast ds_read_b128 + 128 FMAs.
#pragma unroll
    for (int kk = 0; kk < 16; kk += 4) {
        const float w0 = smem[2048 + (kw + kk + 0) * 64 + lane];
        const float w1v = smem[2048 + (kw + kk + 1) * 64 + lane];
        const float w2v = smem[2048 + (kw + kk + 2) * 64 + lane];
        const float w3v = smem[2048 + (kw + kk + 3) * 64 + lane];
#pragma unroll
        for (int b = 0; b < 32; ++b) {
            const float4v x = *(const float4v*)(smem + b * 64 + kw + kk);
            float a = acc[b];
            a = fmaf(x.x, w0, a);
            a = fmaf(x.y, w1v, a);
            a = fmaf(x.z, w2v, a);
            a = fmaf(x.w, w3v, a);
            acc[b] = a;
        }
    }
    __syncthreads();                             // LDS tiles fully consumed

    // --- Waves 1..3 dump partials (24 KB); wave 0 reduces + stores ---
    if (wave) {
#pragma unroll
        for (int j = 0; j < 32; ++j)
            smem[(wave - 1) * 2048 + j * 64 + lane] = acc[j];
    }
    __syncthreads();
    if (wave == 0) {
        if (part) {                              // 2-stage: streaming store
            float* po = part + (size_t)blockIdx.x * BH;
#pragma unroll
            for (int j = 0; j < 32; ++j) {
                const int idx = j * 64 + lane;
                po[idx] = acc[j] + smem[idx] + smem[2048 + idx] + smem[4096 + idx];
            }
        } else {                                 // fallback: sharded atomics
            float* ha = hacc + (blockIdx.x & (NSHARD - 1)) * BH;
#pragma unroll
            for (int j = 0; j < 32; ++j) {
                const int idx = j * 64 + lane;
                atomicAdd(ha + idx,
                          acc[j] + smem[idx] + smem[2048 + idx] + smem[4096 + idx]);
            }
        }
    }
}

// -------- Kernel 2 (2-stage mode only): reduce 2352 partials -> hacc --------
// Round-4 form (proven in the 133.8us total): 256 blocks = 32 batches x 8
// q-slices of 294 rows. Coalesced 256B reads, 16K atomics total.
__global__ __launch_bounds__(256) void k2_reduce(const float* __restrict__ part,
                                                 float* __restrict__ hacc) {
    const int b    = blockIdx.x >> 3;
    const int q    = blockIdx.x & 7;
    const int tid  = threadIdx.x;
    const int lane = tid & 63;
    const int wave = tid >> 6;
    const int r0   = q * 294;                    // 8 * 294 = 2352

    float s = 0.0f;
    for (int r = r0 + wave; r < r0 + 294; r += 4)
        s += part[(size_t)r * BH + b * HID + lane];

    __shared__ float red[3][64];
    if (wave) red[wave - 1][lane] = s;
    __syncthreads();
    if (wave == 0)
        atomicAdd(hacc + b * HID + lane,
                  s + red[0][lane] + red[1][lane] + red[2][lane]);
}

// -------- Kernel 3: head + affine grid + bilinear sampling ------------------
// Round-4 form VERBATIM (round-5's all-wave head + nontemporal stores were
// bundled into a +18us total regression -- reverted).
__global__ __launch_bounds__(1024) void k3_sample(const float* __restrict__ img,
                                                  const float* __restrict__ hacc,
                                                  const float* __restrict__ b1,
                                                  const float* __restrict__ w2,
                                                  const float* __restrict__ b2,
                                                  float* __restrict__ out) {
    const int b     = blockIdx.x / BLK3;
    const int strip = blockIdx.x - b * BLK3;
    const int tid   = threadIdx.x;
    const int lane  = tid & 63;

    __shared__ float sth[6];
    if (tid < 64) {                              // wave 0: lane = hid
        float a = 0.0f;
#pragma unroll
        for (int s = 0; s < NSHARD; ++s)
            a += hacc[s * BH + b * HID + lane];
        const float hv = tanhf(a + b1[lane]);
        const float* w2p = w2 + lane * 6;        // w2 is [HID][6] row-major
        float q[6];
#pragma unroll
        for (int t = 0; t < 6; ++t) q[t] = hv * w2p[t];
#pragma unroll
        for (int off = 32; off >= 1; off >>= 1) {
#pragma unroll
            for (int t = 0; t < 6; ++t) q[t] += __shfl_xor(q[t], off);
        }
        if (lane < 6) sth[lane] = tanhf(q[lane] + b2[lane]);
    }
    __syncthreads();

    const float t0 = sth[0], t1 = sth[1], t2 = sth[2];
    const float t3 = sth[3], t4 = sth[4], t5 = sth[5];

    const float* base = img + (size_t)b * KTOT;
    const int pix = strip * 1024 + tid;
    const int i   = pix / WDIM;
    const int j   = pix - i * WDIM;

    const float xt = (2.0f * (float)j - (float)(WDIM - 1)) / (float)(WDIM - 1);
    const float yt = (2.0f * (float)i - (float)(HDIM - 1)) / (float)(HDIM - 1);

    const float xs = t0 * xt + t1 * yt + t2;
    const float ys = t3 * xt + t4 * yt + t5;

    const float x = 0.5f * (xs + 1.0f) * (float)(WDIM - 1);
    const float y = 0.5f * (ys + 1.0f) * (float)(HDIM - 1);

    const int x0 = (int)floorf(x);
    const int y0 = (int)floorf(y);

    const int x0c = min(max(x0, 0), WDIM - 1);
    const int x1c = min(max(x0 + 1, 0), WDIM - 1);
    const int y0c = min(max(y0, 0), HDIM - 1);
    const int y1c = min(max(y0 + 1, 0), HDIM - 1);

    // Reference computes weights from CLIPPED corner coordinates.
    const float x0f = (float)x0c, x1f = (float)x1c;
    const float y0f = (float)y0c, y1f = (float)y1c;

    const float wa = (x1f - x) * (y1f - y);
    const float wb = (x1f - x) * (y - y0f);
    const float wc = (x - x0f) * (y1f - y);
    const float wd = (x - x0f) * (y - y0f);

    // Both corners of a row are adjacent texels (x1c == x0c+1 whenever the
    // clamp doesn't bind); fetch each row as one 16B + one 8B load. min()
    // keeps the tail access in-bounds.
    int oA = (y0c * WDIM + x0c) * 3;
    int oB = (y1c * WDIM + x0c) * 3;
    oA = min(oA, KTOT - 6);
    oB = min(oB, KTOT - 6);
    const float4u Ar  = *(const float4u*)(base + oA);      // a0 a1 a2 c0
    const float2u Ar2 = *(const float2u*)(base + oA + 4);  // c1 c2
    const float4u Br  = *(const float4u*)(base + oB);      // b0 b1 b2 d0
    const float2u Br2 = *(const float2u*)(base + oB + 4);  // d1 d2

    const float r0 = wa * Ar.x + wb * Br.x + wc * Ar.w  + wd * Br.w;
    const float r1 = wa * Ar.y + wb * Br.y + wc * Ar2.x + wd * Br2.x;
    const float r2 = wa * Ar.z + wb * Br.z + wc * Ar2.y + wd * Br2.y;

    float* po = out + (size_t)b * KTOT + (size_t)pix * 3;
    float2u rv; rv.x = r0; rv.y = r1;
    *(float2u*)po = rv;
    po[2] = r2;
}

extern "C" void kernel_launch(void* const* d_in, const int* in_sizes, int n_in,
                              void* d_out, int out_size, void* d_ws, size_t ws_size,
                              hipStream_t stream) {
    const float* inputs = (const float*)d_in[0];
    const float* w1     = (const float*)d_in[1];
    const float* b1     = (const float*)d_in[2];
    const float* w2     = (const float*)d_in[3];
    const float* b2     = (const float*)d_in[4];
    float* out = (float*)d_out;

    float* hacc = (float*)d_ws;                  // NSHARD * 2048 floats
    float* part = (float*)((char*)d_ws + HACC_BYTES);
    const bool two_stage = ws_size >= HACC_BYTES + PART_BYTES;

    hipMemsetAsync(hacc, 0, HACC_BYTES, stream);
    k1_gemm<<<NBLK1, 256, 0, stream>>>(inputs, w1, hacc,
                                       two_stage ? part : (float*)nullptr);
    if (two_stage)
        k2_reduce<<<256, 256, 0, stream>>>(part, hacc);
    k3_sample<<<BATCH * BLK3, 1024, 0, stream>>>(inputs, hacc, b1, w2, b2, out);
}

// Round 7
// 131.035 us; speedup vs baseline: 1.1892x; 1.0898x over previous
//
#include <hip/hip_runtime.h>
#include <stdint.h>

#define BATCH 32
#define HDIM 224
#define WDIM 224
#define CDIM 3
#define KTOT (HDIM * WDIM * CDIM)   // 150528
#define HID 64
#define KCHUNK 64
#define NBLK1 (KTOT / KCHUNK)       // 2352
#define PIX (HDIM * WDIM)           // 50176
#define BLK3 49                      // blocks per batch: 1024 thr * 1 px

#define NSHARD 16
#define BH (BATCH * HID)             // 2048
#define HACC_BYTES (NSHARD * BH * 4) // 128 KB
#define PART_BYTES ((size_t)NBLK1 * BH * 4)  // 19.3 MB

typedef float float4v __attribute__((ext_vector_type(4)));
// 4-byte-aligned vector loads (texel addresses are only 4B aligned)
typedef float float4u __attribute__((ext_vector_type(4), aligned(4)));
typedef float float2u __attribute__((ext_vector_type(2), aligned(4)));

// ---------------- Kernel 1: part[blk] = flat @ w1 slice (split-K) -----------
// Round-7 change: staging via global->reg->ds_write (NOT global_load_lds).
// Round-5/6 counters showed GLDS serializing at ~400 cyc/instr (per-block
// 8.5us memory wait for 48 GLDS = the k1 wall); the reg path is the
// compiler's native vmcnt-pipelined pattern. It also kills the w1-sink
// pathology structurally: loads feed pre-barrier ds_writes, so they cannot
// be sunk into the FMA loop (rounds 0/2: sunk prefetch, VGPR=40, 52us).
// Geometry as r6: KCHUNK=64, LDS 24KB ([32][64] flat + [64][64] w1), 6
// blocks/CU. Epilogue: coalesced partial store (atomic wall removed r4).
__global__ __launch_bounds__(256, 6) void k1_gemm(const float* __restrict__ flat,
                                                  const float* __restrict__ w1,
                                                  float* __restrict__ hacc,
                                                  float* __restrict__ part) {
    __shared__ float smem[6144];                 // 24 KB
    const int tid  = threadIdx.x;
    const int lane = tid & 63;                   // hid
    const int wave = tid >> 6;
    const int k0   = blockIdx.x * KCHUNK;
    const int kw   = wave * 16;

    // --- Issue all 6 global_load_dwordx4 per thread (pipelined) ---
    float4v rf0, rf1, rw0, rw1, rw2, rw3;
    {
        const int f0 = tid, f1 = tid + 256;      // flat float4 idx 0..511
        rf0 = *(const float4v*)(flat + (size_t)(f0 >> 4) * KTOT + k0 + (f0 & 15) * 4);
        rf1 = *(const float4v*)(flat + (size_t)(f1 >> 4) * KTOT + k0 + (f1 & 15) * 4);
        const float* wbase = w1 + (size_t)k0 * HID;
        rw0 = *(const float4v*)(wbase + (size_t)(tid +   0) * 4);
        rw1 = *(const float4v*)(wbase + (size_t)(tid + 256) * 4);
        rw2 = *(const float4v*)(wbase + (size_t)(tid + 512) * 4);
        rw3 = *(const float4v*)(wbase + (size_t)(tid + 768) * 4);
    }
    // --- ds_write as results land (compiler emits counted vmcnt) ---
    *(float4v*)(smem + (size_t)tid * 4)         = rf0;
    *(float4v*)(smem + (size_t)(tid + 256) * 4) = rf1;
    *(float4v*)(smem + 2048 + (size_t)(tid +   0) * 4) = rw0;
    *(float4v*)(smem + 2048 + (size_t)(tid + 256) * 4) = rw1;
    *(float4v*)(smem + 2048 + (size_t)(tid + 512) * 4) = rw2;
    *(float4v*)(smem + 2048 + (size_t)(tid + 768) * 4) = rw3;
    __syncthreads();

    float acc[32];
#pragma unroll
    for (int j = 0; j < 32; ++j) acc[j] = 0.0f;

    // Per kk-iter: 4 b-invariant w-reads (stride-64-word -> 2-way = free)
    // + 32 broadcast ds_read_b128 + 128 FMAs.
#pragma unroll
    for (int kk = 0; kk < 16; kk += 4) {
        const float w0  = smem[2048 + (kw + kk + 0) * 64 + lane];
        const float w1v = smem[2048 + (kw + kk + 1) * 64 + lane];
        const float w2v = smem[2048 + (kw + kk + 2) * 64 + lane];
        const float w3v = smem[2048 + (kw + kk + 3) * 64 + lane];
#pragma unroll
        for (int b = 0; b < 32; ++b) {
            const float4v x = *(const float4v*)(smem + b * 64 + kw + kk);
            float a = acc[b];
            a = fmaf(x.x, w0, a);
            a = fmaf(x.y, w1v, a);
            a = fmaf(x.z, w2v, a);
            a = fmaf(x.w, w3v, a);
            acc[b] = a;
        }
    }
    __syncthreads();                             // LDS tiles fully consumed

    // --- Waves 1..3 dump partials (24 KB); wave 0 reduces + stores ---
    if (wave) {
#pragma unroll
        for (int j = 0; j < 32; ++j)
            smem[(wave - 1) * 2048 + j * 64 + lane] = acc[j];
    }
    __syncthreads();
    if (wave == 0) {
        if (part) {                              // 2-stage: streaming store
            float* po = part + (size_t)blockIdx.x * BH;
#pragma unroll
            for (int j = 0; j < 32; ++j) {
                const int idx = j * 64 + lane;
                po[idx] = acc[j] + smem[idx] + smem[2048 + idx] + smem[4096 + idx];
            }
        } else {                                 // fallback: sharded atomics
            float* ha = hacc + (blockIdx.x & (NSHARD - 1)) * BH;
#pragma unroll
            for (int j = 0; j < 32; ++j) {
                const int idx = j * 64 + lane;
                atomicAdd(ha + idx,
                          acc[j] + smem[idx] + smem[2048 + idx] + smem[4096 + idx]);
            }
        }
    }
}

// -------- Kernel 2 (2-stage mode): reduce 2352 partials -> 16 shards --------
// Round-7 change: 512 blocks (2/CU, was 1/CU -> latency-bound ~13us), each
// owns shard slot hacc[q][b][*] (q<16, 147 rows each; 16*147=2352). Plain
// coalesced reads + one plain store: zero atomics, zero memset. k3 sums the
// 16 shards (it already did -- byte-identical to r6).
__global__ __launch_bounds__(256) void k2_reduce(const float* __restrict__ part,
                                                 float* __restrict__ hacc) {
    const int b    = blockIdx.x >> 4;            // 0..31
    const int q    = blockIdx.x & 15;            // 0..15
    const int tid  = threadIdx.x;
    const int lane = tid & 63;
    const int wave = tid >> 6;
    const int r0   = q * 147;

    float s = 0.0f;
    for (int r = r0 + wave; r < r0 + 147; r += 4)
        s += part[(size_t)r * BH + b * HID + lane];

    __shared__ float red[3][64];
    if (wave) red[wave - 1][lane] = s;
    __syncthreads();
    if (wave == 0)
        hacc[q * BH + b * HID + lane] =
            s + red[0][lane] + red[1][lane] + red[2][lane];
}

// -------- Kernel 3: head + affine grid + bilinear sampling ------------------
// r4/r6 form VERBATIM (r5's all-wave head + nontemporal stores regressed).
__global__ __launch_bounds__(1024) void k3_sample(const float* __restrict__ img,
                                                  const float* __restrict__ hacc,
                                                  const float* __restrict__ b1,
                                                  const float* __restrict__ w2,
                                                  const float* __restrict__ b2,
                                                  float* __restrict__ out) {
    const int b     = blockIdx.x / BLK3;
    const int strip = blockIdx.x - b * BLK3;
    const int tid   = threadIdx.x;
    const int lane  = tid & 63;

    __shared__ float sth[6];
    if (tid < 64) {                              // wave 0: lane = hid
        float a = 0.0f;
#pragma unroll
        for (int s = 0; s < NSHARD; ++s)
            a += hacc[s * BH + b * HID + lane];
        const float hv = tanhf(a + b1[lane]);
        const float* w2p = w2 + lane * 6;        // w2 is [HID][6] row-major
        float q[6];
#pragma unroll
        for (int t = 0; t < 6; ++t) q[t] = hv * w2p[t];
#pragma unroll
        for (int off = 32; off >= 1; off >>= 1) {
#pragma unroll
            for (int t = 0; t < 6; ++t) q[t] += __shfl_xor(q[t], off);
        }
        if (lane < 6) sth[lane] = tanhf(q[lane] + b2[lane]);
    }
    __syncthreads();

    const float t0 = sth[0], t1 = sth[1], t2 = sth[2];
    const float t3 = sth[3], t4 = sth[4], t5 = sth[5];

    const float* base = img + (size_t)b * KTOT;
    const int pix = strip * 1024 + tid;
    const int i   = pix / WDIM;
    const int j   = pix - i * WDIM;

    const float xt = (2.0f * (float)j - (float)(WDIM - 1)) / (float)(WDIM - 1);
    const float yt = (2.0f * (float)i - (float)(HDIM - 1)) / (float)(HDIM - 1);

    const float xs = t0 * xt + t1 * yt + t2;
    const float ys = t3 * xt + t4 * yt + t5;

    const float x = 0.5f * (xs + 1.0f) * (float)(WDIM - 1);
    const float y = 0.5f * (ys + 1.0f) * (float)(HDIM - 1);

    const int x0 = (int)floorf(x);
    const int y0 = (int)floorf(y);

    const int x0c = min(max(x0, 0), WDIM - 1);
    const int x1c = min(max(x0 + 1, 0), WDIM - 1);
    const int y0c = min(max(y0, 0), HDIM - 1);
    const int y1c = min(max(y0 + 1, 0), HDIM - 1);

    // Reference computes weights from CLIPPED corner coordinates.
    const float x0f = (float)x0c, x1f = (float)x1c;
    const float y0f = (float)y0c, y1f = (float)y1c;

    const float wa = (x1f - x) * (y1f - y);
    const float wb = (x1f - x) * (y - y0f);
    const float wc = (x - x0f) * (y1f - y);
    const float wd = (x - x0f) * (y - y0f);

    // Both corners of a row are adjacent texels (x1c == x0c+1 whenever the
    // clamp doesn't bind); fetch each row as one 16B + one 8B load. min()
    // keeps the tail access in-bounds.
    int oA = (y0c * WDIM + x0c) * 3;
    int oB = (y1c * WDIM + x0c) * 3;
    oA = min(oA, KTOT - 6);
    oB = min(oB, KTOT - 6);
    const float4u Ar  = *(const float4u*)(base + oA);      // a0 a1 a2 c0
    const float2u Ar2 = *(const float2u*)(base + oA + 4);  // c1 c2
    const float4u Br  = *(const float4u*)(base + oB);      // b0 b1 b2 d0
    const float2u Br2 = *(const float2u*)(base + oB + 4);  // d1 d2

    const float r0 = wa * Ar.x + wb * Br.x + wc * Ar.w  + wd * Br.w;
    const float r1 = wa * Ar.y + wb * Br.y + wc * Ar2.x + wd * Br2.x;
    const float r2 = wa * Ar.z + wb * Br.z + wc * Ar2.y + wd * Br2.y;

    float* po = out + (size_t)b * KTOT + (size_t)pix * 3;
    float2u rv; rv.x = r0; rv.y = r1;
    *(float2u*)po = rv;
    po[2] = r2;
}

extern "C" void kernel_launch(void* const* d_in, const int* in_sizes, int n_in,
                              void* d_out, int out_size, void* d_ws, size_t ws_size,
                              hipStream_t stream) {
    const float* inputs = (const float*)d_in[0];
    const float* w1     = (const float*)d_in[1];
    const float* b1     = (const float*)d_in[2];
    const float* w2     = (const float*)d_in[3];
    const float* b2     = (const float*)d_in[4];
    float* out = (float*)d_out;

    float* hacc = (float*)d_ws;                  // NSHARD * 2048 floats
    float* part = (float*)((char*)d_ws + HACC_BYTES);
    const bool two_stage = ws_size >= HACC_BYTES + PART_BYTES;

    if (two_stage) {
        // k2 writes all 16 shards -> no memset, no atomics anywhere.
        k1_gemm<<<NBLK1, 256, 0, stream>>>(inputs, w1, hacc, part);
        k2_reduce<<<512, 256, 0, stream>>>(part, hacc);
    } else {
        hipMemsetAsync(hacc, 0, HACC_BYTES, stream);
        k1_gemm<<<NBLK1, 256, 0, stream>>>(inputs, w1, hacc, (float*)nullptr);
    }
    k3_sample<<<BATCH * BLK3, 1024, 0, stream>>>(inputs, hacc, b1, w2, b2, out);
}